// Round 14
// baseline (1763.069 us; speedup 1.0000x reference)
//
#include <hip/hip_runtime.h>
#include <hip/hip_bf16.h>
#include <hip/hip_cooperative_groups.h>

namespace cg = cooperative_groups;

#define NN 50000
#define NE 600000
#define IN_DIM 128
#define HC 128      // H*C
#define NH 4
#define NC 32
#define NEG_SLOPE 0.2f

#define NTHR 256
#define NTILE 196           // ceil(NN/256) scan tiles
#define NU128 1563          // ceil(NN/32) 32-row gemm wave-units
#define WT_TOTAL 86016

typedef __attribute__((ext_vector_type(8))) short short8;
typedef __attribute__((ext_vector_type(4))) float floatx4;
typedef __attribute__((ext_vector_type(8))) unsigned short ushort8v;

__device__ __forceinline__ float bf2f(unsigned short u) {
    return __uint_as_float(((unsigned)u) << 16);
}
__device__ __forceinline__ unsigned short f2bf(float f) {
    unsigned u = __float_as_uint(f);
    unsigned r = (u + 0x7FFFu + ((u >> 16) & 1u)) >> 16;   // RNE
    return (unsigned short)r;
}

// ---------------- shared transpose indexing: wt[idx], idx in [0, 86016) ----------------
__device__ __forceinline__ void wt_write(int idx, unsigned short* __restrict__ wt,
                                         const float* const* Wp) {
    // Wp = {W0,S0,W1,S1,W2,S2}
    const float* W; int OD; int base; int sel;
    int r = idx >> 14;
    if (idx < 81920) { sel = r; OD = 128; base = r << 14; }
    else             { sel = 5; OD = 32;  base = 81920; }
    W = Wp[sel];
    int off = idx - base;
    int n = off >> 7, k = off & 127;
    wt[idx] = f2bf(W[(size_t)k * OD + n]);
}

// ============ LDS-free MFMA GEMM wave: 32 rows x OD cols, K=128 ============
template<typename AT, int OD, int OBF>
__device__ __forceinline__ void gemm_wave(
    const AT* __restrict__ x, const unsigned short* __restrict__ Wt,
    const float* __restrict__ b, void* __restrict__ yv, int n0, int lane) {
    int quad = lane >> 4, l16 = lane & 15;
    floatx4 acc[2][OD / 16];
    #pragma unroll
    for (int i = 0; i < 2; ++i)
        #pragma unroll
        for (int j = 0; j < OD / 16; ++j) acc[i][j] = (floatx4){0.f, 0.f, 0.f, 0.f};

    int r0 = n0 + l16;      if (r0 >= NN) r0 = NN - 1;
    int r1 = n0 + 16 + l16; if (r1 >= NN) r1 = NN - 1;

    #pragma unroll
    for (int ks = 0; ks < 4; ++ks) {
        int kb = ks * 32 + quad * 8;
        short8 xb0, xb1;
        if constexpr (sizeof(AT) == 4) {
            const float* xr = (const float*)x;
            float4 v0 = *(const float4*)&xr[(size_t)r0 * IN_DIM + kb];
            float4 v1 = *(const float4*)&xr[(size_t)r0 * IN_DIM + kb + 4];
            float4 u0 = *(const float4*)&xr[(size_t)r1 * IN_DIM + kb];
            float4 u1 = *(const float4*)&xr[(size_t)r1 * IN_DIM + kb + 4];
            xb0 = (short8){(short)f2bf(v0.x), (short)f2bf(v0.y), (short)f2bf(v0.z), (short)f2bf(v0.w),
                           (short)f2bf(v1.x), (short)f2bf(v1.y), (short)f2bf(v1.z), (short)f2bf(v1.w)};
            xb1 = (short8){(short)f2bf(u0.x), (short)f2bf(u0.y), (short)f2bf(u0.z), (short)f2bf(u0.w),
                           (short)f2bf(u1.x), (short)f2bf(u1.y), (short)f2bf(u1.z), (short)f2bf(u1.w)};
        } else {
            xb0 = *(const short8*)&((const unsigned short*)x)[(size_t)r0 * IN_DIM + kb];
            xb1 = *(const short8*)&((const unsigned short*)x)[(size_t)r1 * IN_DIM + kb];
        }
        #pragma unroll
        for (int tc = 0; tc < OD / 16; ++tc) {
            short8 af = *(const short8*)&Wt[(size_t)(tc * 16 + l16) * 128 + kb];
            acc[0][tc] = __builtin_amdgcn_mfma_f32_16x16x32_bf16(af, xb0, acc[0][tc], 0, 0, 0);
            acc[1][tc] = __builtin_amdgcn_mfma_f32_16x16x32_bf16(af, xb1, acc[1][tc], 0, 0, 0);
        }
    }

    #pragma unroll
    for (int tc = 0; tc < OD / 16; ++tc) {
        int cbase = tc * 16 + quad * 4;
        float4 bv = *(const float4*)&b[cbase];
        #pragma unroll
        for (int i = 0; i < 2; ++i) {
            int node = n0 + i * 16 + l16;
            if (node < NN) {
                float v0 = acc[i][tc][0] + bv.x;
                float v1 = acc[i][tc][1] + bv.y;
                float v2 = acc[i][tc][2] + bv.z;
                float v3 = acc[i][tc][3] + bv.w;
                if constexpr (OBF) {
                    ushort4 pk = {f2bf(v0), f2bf(v1), f2bf(v2), f2bf(v3)};
                    *(ushort4*)&((unsigned short*)yv)[(size_t)node * OD + cbase] = pk;
                } else {
                    *(float4*)&((float*)yv)[(size_t)node * OD + cbase] = (float4){v0, v1, v2, v3};
                }
            }
        }
    }
}

// ---------------- per-node GATv2 (1 wave, 4 slots x 16 lanes) ----------------
__device__ __forceinline__ void gat_node(
    int n, int lane, const unsigned short* __restrict__ h, const int* __restrict__ rowptr,
    const int* __restrict__ csr_src, const float* __restrict__ att,
    const float* __restrict__ bias, const float* __restrict__ skip,
    void* __restrict__ out, int last) {
    int slot = lane >> 4;
    int t = lane & 15;

    ushort8v hdv = *(const ushort8v*)(h + (size_t)n * HC + t * 8);
    float hd[8], av[8];
    #pragma unroll
    for (int c = 0; c < 8; ++c) hd[c] = bf2f(hdv[c]);
    float4 av0 = ((const float4*)att)[t * 2];
    float4 av1 = ((const float4*)att)[t * 2 + 1];
    av[0] = av0.x; av[1] = av0.y; av[2] = av0.z; av[3] = av0.w;
    av[4] = av1.x; av[5] = av1.y; av[6] = av1.z; av[7] = av1.w;

    int beg = rowptr[n], end = rowptr[n + 1];
    float l = 0.f;
    float acc[8] = {};

    int i0 = beg + slot;
    ushort8v b0 = 0, b1 = 0;
    if (i0 < end)     b0 = *(const ushort8v*)(h + (size_t)csr_src[i0] * HC + t * 8);
    if (i0 + 4 < end) b1 = *(const ushort8v*)(h + (size_t)csr_src[i0 + 4] * HC + t * 8);

    for (int i = i0; i < end; i += 4) {
        float hs[8];
        #pragma unroll
        for (int c = 0; c < 8; ++c) hs[c] = bf2f(b0[c]);
        b0 = b1;
        if (i + 8 < end)
            b1 = *(const ushort8v*)(h + (size_t)csr_src[i + 8] * HC + t * 8);
        float part = 0.f;
        #pragma unroll
        for (int c = 0; c < 8; ++c) {
            float v = hs[c] + hd[c];
            float lr = fmaxf(v, 0.f) + NEG_SLOPE * fminf(v, 0.f);
            part += lr * av[c];
        }
        part += __shfl_xor(part, 1, 64);
        part += __shfl_xor(part, 2, 64);
        float p = __expf(part);
        #pragma unroll
        for (int c = 0; c < 8; ++c) acc[c] += p * hs[c];
        l += p;
    }

    l += __shfl_xor(l, 16, 64);
    l += __shfl_xor(l, 32, 64);
    #pragma unroll
    for (int c = 0; c < 8; ++c) {
        acc[c] += __shfl_xor(acc[c], 16, 64);
        acc[c] += __shfl_xor(acc[c], 32, 64);
    }

    float inv = 1.f / fmaxf(l, 1e-16f);
    float o[8];
    #pragma unroll
    for (int c = 0; c < 8; ++c) o[c] = acc[c] * inv;

    if (!last) {
        if (lane < 16) {
            float4 bv0 = ((const float4*)bias)[t * 2];
            float4 bv1 = ((const float4*)bias)[t * 2 + 1];
            float4 sk0 = ((const float4*)(skip + (size_t)n * HC))[t * 2];
            float4 sk1 = ((const float4*)(skip + (size_t)n * HC))[t * 2 + 1];
            float bb[8] = {bv0.x, bv0.y, bv0.z, bv0.w, bv1.x, bv1.y, bv1.z, bv1.w};
            float sk[8] = {sk0.x, sk0.y, sk0.z, sk0.w, sk1.x, sk1.y, sk1.z, sk1.w};
            ushort8v ov;
            #pragma unroll
            for (int c = 0; c < 8; ++c) {
                float r = o[c] + bb[c] + sk[c];
                r = r > 0.f ? r : (__expf(r) - 1.f);   // ELU
                ov[c] = f2bf(r);
            }
            *(ushort8v*)((unsigned short*)out + (size_t)n * HC + t * 8) = ov;
        }
    } else {
        float r4[8], r8[8], r12[8];
        #pragma unroll
        for (int c = 0; c < 8; ++c) {
            r4[c]  = __shfl_down(o[c], 4, 64);
            r8[c]  = __shfl_down(o[c], 8, 64);
            r12[c] = __shfl_down(o[c], 12, 64);
        }
        if (lane < 4) {
            float* op = (float*)out + (size_t)n * NC + lane * 8;
            float rr[8];
            #pragma unroll
            for (int c = 0; c < 8; ++c) {
                rr[c] = 0.25f * (o[c] + r4[c] + r8[c] + r12[c])
                      + bias[lane * 8 + c] + skip[(size_t)n * NC + lane * 8 + c];
            }
            *(float4*)op = (float4){rr[0], rr[1], rr[2], rr[3]};
            *(float4*)(op + 4) = (float4){rr[4], rr[5], rr[6], rr[7]};
        }
    }
}

// ---------------- parameter block ----------------
struct MegaP {
    const float* x0;
    const int* src;
    const int* dst;
    unsigned short* xbuf;
    unsigned short* h;
    float* skip;
    int* deg; int* rowptr; int* cursor; int* partial; int* blocksum; int* csr_src;
    unsigned short* wt;
    const float* W[3]; const float* S[3];
    const float* linb[3]; const float* att[3]; const float* bias[3]; const float* skipb[3];
    float* out;
};

// ================= cooperative mega-kernel (grid-size agnostic) =================
__global__ __launch_bounds__(NTHR, 4) void mega(MegaP p) {
    cg::grid_group grid = cg::this_grid();
    int tid = threadIdx.x, bid = blockIdx.x;
    int nb = gridDim.x;
    int gtid = bid * NTHR + tid;
    int gstride = nb * NTHR;
    int gwave = bid * 4 + (tid >> 6);
    int nwaves = nb * 4;
    int lane = tid & 63;
    __shared__ int sh[NTHR];
    const float* Wp[6] = {p.W[0], p.S[0], p.W[1], p.S[1], p.W[2], p.S[2]};

    // phase 0: zero deg + weight transpose
    for (int i = gtid; i < NN; i += gstride) p.deg[i] = 0;
    for (int idx = gtid; idx < WT_TOTAL; idx += gstride) wt_write(idx, p.wt, Wp);
    __threadfence(); grid.sync();

    // phase 1: degree histogram
    for (int e = gtid; e < NE; e += gstride)
        atomicAdd(&p.deg[p.dst[e]], 1);
    __threadfence(); grid.sync();

    // phase 2: per-tile inclusive scan (block-stride over tiles)
    for (int tile = bid; tile < NTILE; tile += nb) {
        int i = tile * NTHR + tid;
        int d = (i < NN) ? p.deg[i] : 0;
        sh[tid] = d;
        __syncthreads();
        #pragma unroll
        for (int off = 1; off < NTHR; off <<= 1) {
            int v = (tid >= off) ? sh[tid - off] : 0;
            __syncthreads();
            sh[tid] += v;
            __syncthreads();
        }
        if (i < NN) p.partial[i] = sh[tid];
        if (tid == NTHR - 1) p.blocksum[tile] = sh[tid];
        __syncthreads();
    }
    __threadfence(); grid.sync();

    // phase 3: exclusive scan of tile sums (block 0; NTILE=196 < 256)
    if (bid == 0) {
        int v = (tid < NTILE) ? p.blocksum[tid] : 0;
        sh[tid] = v;
        __syncthreads();
        #pragma unroll
        for (int off = 1; off < NTHR; off <<= 1) {
            int u = (tid >= off) ? sh[tid - off] : 0;
            __syncthreads();
            sh[tid] += u;
            __syncthreads();
        }
        if (tid < NTILE) p.blocksum[tid] = sh[tid] - v;
    }
    __threadfence(); grid.sync();

    // phase 4: apply -> rowptr, cursor
    for (int i = gtid; i < NN; i += gstride) {
        int inc = p.partial[i] + p.blocksum[i >> 8];
        p.rowptr[i + 1] = inc;
        p.cursor[i] = inc - p.deg[i];
        if (i == 0) p.rowptr[0] = 0;
    }
    __threadfence(); grid.sync();

    // phase 5: scatter edges to CSR
    for (int e = gtid; e < NE; e += gstride) {
        int d = p.dst[e];
        int pos = atomicAdd(&p.cursor[d], 1);
        p.csr_src[pos] = p.src[e];
    }
    __threadfence(); grid.sync();

    // layers
    for (int l = 0; l < 3; ++l) {
        const unsigned short* wtW = p.wt + (l == 0 ? 0 : l == 1 ? 32768 : 65536);
        const unsigned short* wtS = p.wt + (l == 0 ? 16384 : l == 1 ? 49152 : 81920);

        for (int u = gwave; u < 2 * NU128; u += nwaves) {
            if (l == 0) {
                if (u < NU128) gemm_wave<float, 128, 1>(p.x0, wtW, p.linb[0], p.h, u * 32, lane);
                else           gemm_wave<float, 128, 0>(p.x0, wtS, p.skipb[0], p.skip, (u - NU128) * 32, lane);
            } else if (l == 1) {
                if (u < NU128) gemm_wave<unsigned short, 128, 1>(p.xbuf, wtW, p.linb[1], p.h, u * 32, lane);
                else           gemm_wave<unsigned short, 128, 0>(p.xbuf, wtS, p.skipb[1], p.skip, (u - NU128) * 32, lane);
            } else {
                if (u < NU128) gemm_wave<unsigned short, 128, 1>(p.xbuf, wtW, p.linb[2], p.h, u * 32, lane);
                else           gemm_wave<unsigned short, 32, 0>(p.xbuf, wtS, p.skipb[2], p.skip, (u - NU128) * 32, lane);
            }
        }
        __threadfence(); grid.sync();

        void* outp = (l < 2) ? (void*)p.xbuf : (void*)p.out;
        for (int n = gwave; n < NN; n += nwaves)
            gat_node(n, lane, p.h, p.rowptr, p.csr_src, p.att[l], p.bias[l], p.skip, outp, l == 2);
        if (l < 2) { __threadfence(); grid.sync(); }
    }
}

// ================= fallback multi-kernel path (R12-proven) =================
__global__ void k_transpose(MegaP p) {
    const float* Wp[6] = {p.W[0], p.S[0], p.W[1], p.S[1], p.W[2], p.S[2]};
    int idx = blockIdx.x * blockDim.x + threadIdx.x;
    if (idx < WT_TOTAL) wt_write(idx, p.wt, Wp);
}
__global__ void k_hist(const int* __restrict__ dst, int* __restrict__ deg) {
    int e = blockIdx.x * blockDim.x + threadIdx.x;
    if (e < NE) atomicAdd(&deg[dst[e]], 1);
}
__global__ __launch_bounds__(NTHR) void k_scan1(const int* __restrict__ deg,
                                                int* __restrict__ partial,
                                                int* __restrict__ blocksum) {
    __shared__ int sh[NTHR];
    int b = blockIdx.x, t = threadIdx.x;
    int i = b * NTHR + t;
    int d = (i < NN) ? deg[i] : 0;
    sh[t] = d;
    __syncthreads();
    #pragma unroll
    for (int off = 1; off < NTHR; off <<= 1) {
        int v = (t >= off) ? sh[t - off] : 0;
        __syncthreads();
        sh[t] += v;
        __syncthreads();
    }
    if (i < NN) partial[i] = sh[t];
    if (t == NTHR - 1) blocksum[b] = sh[t];
}
__global__ __launch_bounds__(NTHR) void k_scan2(int* __restrict__ blocksum) {
    __shared__ int sh[NTHR];
    int t = threadIdx.x;
    int v = (t < NTILE) ? blocksum[t] : 0;
    sh[t] = v;
    __syncthreads();
    #pragma unroll
    for (int off = 1; off < NTHR; off <<= 1) {
        int u = (t >= off) ? sh[t - off] : 0;
        __syncthreads();
        sh[t] += u;
        __syncthreads();
    }
    if (t < NTILE) blocksum[t] = sh[t] - v;
}
__global__ void k_scan3(const int* __restrict__ deg, const int* __restrict__ partial,
                        const int* __restrict__ blocksum, int* __restrict__ rowptr,
                        int* __restrict__ cursor) {
    int i = blockIdx.x * blockDim.x + threadIdx.x;
    if (i >= NN) return;
    int inc = partial[i] + blocksum[i >> 8];
    rowptr[i + 1] = inc;
    cursor[i] = inc - deg[i];
    if (i == 0) rowptr[0] = 0;
}
__global__ void k_scatter(const int* __restrict__ src, const int* __restrict__ dst,
                          int* __restrict__ cursor, int* __restrict__ csr_src) {
    int e = blockIdx.x * blockDim.x + threadIdx.x;
    if (e >= NE) return;
    int d = dst[e];
    int pos = atomicAdd(&cursor[d], 1);
    csr_src[pos] = src[e];
}
template<typename AT>
__global__ __launch_bounds__(256) void k_gemm_dual_lf(
    const AT* __restrict__ x,
    const unsigned short* __restrict__ Wta, const float* __restrict__ ba, unsigned short* __restrict__ ya,
    const unsigned short* __restrict__ Wtb, const float* __restrict__ bb, float* __restrict__ yb) {
    int wid = threadIdx.x >> 6, lane = threadIdx.x & 63;
    int n0 = (blockIdx.x * 4 + wid) * 32;
    if (n0 >= NN) return;
    if (blockIdx.y == 0) gemm_wave<AT, 128, 1>(x, Wta, ba, (void*)ya, n0, lane);
    else                 gemm_wave<AT, 128, 0>(x, Wtb, bb, (void*)yb, n0, lane);
}
__global__ __launch_bounds__(256) void k_gemm_dual_l2(
    const unsigned short* __restrict__ x,
    const unsigned short* __restrict__ Wta, const float* __restrict__ ba, unsigned short* __restrict__ ya,
    const unsigned short* __restrict__ Wtb, const float* __restrict__ bb, float* __restrict__ yb) {
    int wid = threadIdx.x >> 6, lane = threadIdx.x & 63;
    int n0 = (blockIdx.x * 4 + wid) * 32;
    if (n0 >= NN) return;
    if (blockIdx.y == 0) gemm_wave<unsigned short, 128, 1>(x, Wta, ba, (void*)ya, n0, lane);
    else                 gemm_wave<unsigned short, 32, 0>(x, Wtb, bb, (void*)yb, n0, lane);
}
__global__ __launch_bounds__(256) void k_gat(
    const unsigned short* __restrict__ h, const int* __restrict__ rowptr,
    const int* __restrict__ csr_src, const float* __restrict__ att,
    const float* __restrict__ bias, const float* __restrict__ skip,
    void* __restrict__ out, int last) {
    int wid = threadIdx.x >> 6;
    int n = blockIdx.x * 4 + wid;
    if (n >= NN) return;
    gat_node(n, threadIdx.x & 63, h, rowptr, csr_src, att, bias, skip, out, last);
}

extern "C" void kernel_launch(void* const* d_in, const int* in_sizes, int n_in,
                              void* d_out, int out_size, void* d_ws, size_t ws_size,
                              hipStream_t stream) {
    const float* x0 = (const float*)d_in[0];
    const int* ei = (const int*)d_in[1];

    unsigned short* xbuf = (unsigned short*)d_ws;            // NN*HC bf16
    unsigned short* h    = xbuf + (size_t)NN * HC;           // NN*HC bf16
    float* skip  = (float*)(h + (size_t)NN * HC);            // NN*HC fp32
    int* deg     = (int*)(skip + (size_t)NN * HC);           // NN
    int* rowptr  = deg + NN;                                 // NN+1
    int* cursor  = rowptr + NN + 1;                          // NN
    int* partial = cursor + NN;                              // NN
    int* blocksum = partial + NN;                            // NTILE
    uintptr_t pa = (uintptr_t)(blocksum + NTILE);
    pa = (pa + 15) & ~(uintptr_t)15;
    unsigned short* wt = (unsigned short*)pa;                // WT_TOTAL bf16
    int* csr_src = (int*)(wt + WT_TOTAL);                    // NE

    MegaP p;
    p.x0 = x0;
    p.src = ei;
    p.dst = ei + NE;
    p.xbuf = xbuf; p.h = h; p.skip = skip;
    p.deg = deg; p.rowptr = rowptr; p.cursor = cursor;
    p.partial = partial; p.blocksum = blocksum; p.csr_src = csr_src;
    p.wt = wt;
    for (int l = 0; l < 3; ++l) {
        p.W[l]     = (const float*)d_in[2 + 6 * l + 0];
        p.linb[l]  = (const float*)d_in[2 + 6 * l + 1];
        p.att[l]   = (const float*)d_in[2 + 6 * l + 2];
        p.bias[l]  = (const float*)d_in[2 + 6 * l + 3];
        p.S[l]     = (const float*)d_in[2 + 6 * l + 4];
        p.skipb[l] = (const float*)d_in[2 + 6 * l + 5];
    }
    p.out = (float*)d_out;

    // ---- try cooperative path with occupancy-clamped grid ----
    bool coop_ok = false;
    int coop_attr = 0;
    if (hipDeviceGetAttribute(&coop_attr, hipDeviceAttributeCooperativeLaunch, 0) == hipSuccess
        && coop_attr) {
        int maxB = 0, ncu = 0;
        if (hipOccupancyMaxActiveBlocksPerMultiprocessor(&maxB, mega, NTHR, 0) == hipSuccess
            && hipDeviceGetAttribute(&ncu, hipDeviceAttributeMultiprocessorCount, 0) == hipSuccess) {
            int nblk = maxB * ncu;
            if (nblk > 1024) nblk = 1024;
            if (nblk >= NTILE) {
                void* args[] = {&p};
                hipError_t err = hipLaunchCooperativeKernel((const void*)mega,
                                                            dim3(nblk), dim3(NTHR), args, 0, stream);
                if (err == hipSuccess) coop_ok = true;
                else (void)hipGetLastError();   // clear error state before fallback
            }
        }
    }

    if (!coop_ok) {
        // ---- fallback: proven multi-kernel path ----
        const int* src = ei;
        const int* dst = ei + NE;
        hipMemsetAsync(deg, 0, (size_t)NN * sizeof(int), stream);
        k_transpose<<<(WT_TOTAL + 255) / 256, 256, 0, stream>>>(p);
        k_hist<<<(NE + 255) / 256, 256, 0, stream>>>(dst, deg);
        k_scan1<<<NTILE, NTHR, 0, stream>>>(deg, partial, blocksum);
        k_scan2<<<1, NTHR, 0, stream>>>(blocksum);
        k_scan3<<<(NN + 255) / 256, 256, 0, stream>>>(deg, partial, blocksum, rowptr, cursor);
        k_scatter<<<(NE + 255) / 256, 256, 0, stream>>>(src, dst, cursor, csr_src);

        const int GLF = (NN + 127) / 128;
        const int GGAT = (NN + 3) / 4;
        unsigned short* wtW[3] = {wt, wt + 32768, wt + 65536};
        unsigned short* wtS[3] = {wt + 16384, wt + 49152, wt + 81920};

        for (int l = 0; l < 3; ++l) {
            if (l == 0) {
                k_gemm_dual_lf<float><<<dim3(GLF, 2), 256, 0, stream>>>(
                    x0, wtW[0], p.linb[0], h, wtS[0], p.skipb[0], skip);
            } else if (l == 1) {
                k_gemm_dual_lf<unsigned short><<<dim3(GLF, 2), 256, 0, stream>>>(
                    xbuf, wtW[1], p.linb[1], h, wtS[1], p.skipb[1], skip);
            } else {
                k_gemm_dual_l2<<<dim3(GLF, 2), 256, 0, stream>>>(
                    xbuf, wtW[2], p.linb[2], h, wtS[2], p.skipb[2], skip);
            }
            void* outp = (l < 2) ? (void*)xbuf : (void*)d_out;
            k_gat<<<GGAT, 256, 0, stream>>>(h, rowptr, csr_src, p.att[l], p.bias[l], skip, outp, l == 2);
        }
    }
}

// Round 15
// 364.183 us; speedup vs baseline: 4.8412x; 4.8412x over previous
//
#include <hip/hip_runtime.h>
#include <hip/hip_bf16.h>

#define NN 50000
#define NE 600000
#define IN_DIM 128
#define HC 128      // H*C
#define NH 4
#define NC 32
#define NEG_SLOPE 0.2f

#define NTHR 256
#define NTILE 196           // ceil(NN/256) scan tiles
#define WT_TOTAL 86016

typedef __attribute__((ext_vector_type(8))) short short8;
typedef __attribute__((ext_vector_type(4))) float floatx4;
typedef __attribute__((ext_vector_type(8))) unsigned short ushort8v;

__device__ __forceinline__ float bf2f(unsigned short u) {
    return __uint_as_float(((unsigned)u) << 16);
}
__device__ __forceinline__ unsigned short f2bf(float f) {
    unsigned u = __float_as_uint(f);
    unsigned r = (u + 0x7FFFu + ((u >> 16) & 1u)) >> 16;   // RNE
    return (unsigned short)r;
}

// ============ LDS-free MFMA GEMM wave: 32 rows x OD cols, K=128 ============
// mfma(A=Wt frag, B=x frag) -> D[m=channel][n=node]; wide per-node stores.
template<typename AT, int OD, int OBF>
__device__ __forceinline__ void gemm_wave(
    const AT* __restrict__ x, const unsigned short* __restrict__ Wt,
    const float* __restrict__ b, void* __restrict__ yv, int n0, int lane) {
    int quad = lane >> 4, l16 = lane & 15;
    floatx4 acc[2][OD / 16];
    #pragma unroll
    for (int i = 0; i < 2; ++i)
        #pragma unroll
        for (int j = 0; j < OD / 16; ++j) acc[i][j] = (floatx4){0.f, 0.f, 0.f, 0.f};

    int r0 = n0 + l16;      if (r0 >= NN) r0 = NN - 1;
    int r1 = n0 + 16 + l16; if (r1 >= NN) r1 = NN - 1;

    #pragma unroll
    for (int ks = 0; ks < 4; ++ks) {
        int kb = ks * 32 + quad * 8;
        short8 xb0, xb1;
        if constexpr (sizeof(AT) == 4) {
            const float* xr = (const float*)x;
            float4 v0 = *(const float4*)&xr[(size_t)r0 * IN_DIM + kb];
            float4 v1 = *(const float4*)&xr[(size_t)r0 * IN_DIM + kb + 4];
            float4 u0 = *(const float4*)&xr[(size_t)r1 * IN_DIM + kb];
            float4 u1 = *(const float4*)&xr[(size_t)r1 * IN_DIM + kb + 4];
            xb0 = (short8){(short)f2bf(v0.x), (short)f2bf(v0.y), (short)f2bf(v0.z), (short)f2bf(v0.w),
                           (short)f2bf(v1.x), (short)f2bf(v1.y), (short)f2bf(v1.z), (short)f2bf(v1.w)};
            xb1 = (short8){(short)f2bf(u0.x), (short)f2bf(u0.y), (short)f2bf(u0.z), (short)f2bf(u0.w),
                           (short)f2bf(u1.x), (short)f2bf(u1.y), (short)f2bf(u1.z), (short)f2bf(u1.w)};
        } else {
            xb0 = *(const short8*)&((const unsigned short*)x)[(size_t)r0 * IN_DIM + kb];
            xb1 = *(const short8*)&((const unsigned short*)x)[(size_t)r1 * IN_DIM + kb];
        }
        #pragma unroll
        for (int tc = 0; tc < OD / 16; ++tc) {
            short8 af = *(const short8*)&Wt[(size_t)(tc * 16 + l16) * 128 + kb];
            acc[0][tc] = __builtin_amdgcn_mfma_f32_16x16x32_bf16(af, xb0, acc[0][tc], 0, 0, 0);
            acc[1][tc] = __builtin_amdgcn_mfma_f32_16x16x32_bf16(af, xb1, acc[1][tc], 0, 0, 0);
        }
    }

    #pragma unroll
    for (int tc = 0; tc < OD / 16; ++tc) {
        int cbase = tc * 16 + quad * 4;
        float4 bv = *(const float4*)&b[cbase];
        #pragma unroll
        for (int i = 0; i < 2; ++i) {
            int node = n0 + i * 16 + l16;
            if (node < NN) {
                float v0 = acc[i][tc][0] + bv.x;
                float v1 = acc[i][tc][1] + bv.y;
                float v2 = acc[i][tc][2] + bv.z;
                float v3 = acc[i][tc][3] + bv.w;
                if constexpr (OBF) {
                    ushort4 pk = {f2bf(v0), f2bf(v1), f2bf(v2), f2bf(v3)};
                    *(ushort4*)&((unsigned short*)yv)[(size_t)node * OD + cbase] = pk;
                } else {
                    *(float4*)&((float*)yv)[(size_t)node * OD + cbase] = (float4){v0, v1, v2, v3};
                }
            }
        }
    }
}

// ---------------- per-node GATv2 (1 wave, 4 slots x 16 lanes) ----------------
__device__ __forceinline__ void gat_node(
    int n, int lane, const unsigned short* __restrict__ h, const int* __restrict__ rowptr,
    const int* __restrict__ csr_src, const float* __restrict__ att,
    const float* __restrict__ bias, const float* __restrict__ skip,
    void* __restrict__ out, int last) {
    int slot = lane >> 4;
    int t = lane & 15;

    ushort8v hdv = *(const ushort8v*)(h + (size_t)n * HC + t * 8);
    float hd[8], av[8];
    #pragma unroll
    for (int c = 0; c < 8; ++c) hd[c] = bf2f(hdv[c]);
    float4 av0 = ((const float4*)att)[t * 2];
    float4 av1 = ((const float4*)att)[t * 2 + 1];
    av[0] = av0.x; av[1] = av0.y; av[2] = av0.z; av[3] = av0.w;
    av[4] = av1.x; av[5] = av1.y; av[6] = av1.z; av[7] = av1.w;

    int beg = rowptr[n], end = rowptr[n + 1];
    float l = 0.f;
    float acc[8] = {};

    int i0 = beg + slot;
    ushort8v b0 = 0, b1 = 0;
    if (i0 < end)     b0 = *(const ushort8v*)(h + (size_t)csr_src[i0] * HC + t * 8);
    if (i0 + 4 < end) b1 = *(const ushort8v*)(h + (size_t)csr_src[i0 + 4] * HC + t * 8);

    for (int i = i0; i < end; i += 4) {
        float hs[8];
        #pragma unroll
        for (int c = 0; c < 8; ++c) hs[c] = bf2f(b0[c]);
        b0 = b1;
        if (i + 8 < end)
            b1 = *(const ushort8v*)(h + (size_t)csr_src[i + 8] * HC + t * 8);
        float part = 0.f;
        #pragma unroll
        for (int c = 0; c < 8; ++c) {
            float v = hs[c] + hd[c];
            float lr = fmaxf(v, 0.f) + NEG_SLOPE * fminf(v, 0.f);
            part += lr * av[c];
        }
        part += __shfl_xor(part, 1, 64);
        part += __shfl_xor(part, 2, 64);
        float p = __expf(part);
        #pragma unroll
        for (int c = 0; c < 8; ++c) acc[c] += p * hs[c];
        l += p;
    }

    l += __shfl_xor(l, 16, 64);
    l += __shfl_xor(l, 32, 64);
    #pragma unroll
    for (int c = 0; c < 8; ++c) {
        acc[c] += __shfl_xor(acc[c], 16, 64);
        acc[c] += __shfl_xor(acc[c], 32, 64);
    }

    float inv = 1.f / fmaxf(l, 1e-16f);
    float o[8];
    #pragma unroll
    for (int c = 0; c < 8; ++c) o[c] = acc[c] * inv;

    if (!last) {
        if (lane < 16) {
            float4 bv0 = ((const float4*)bias)[t * 2];
            float4 bv1 = ((const float4*)bias)[t * 2 + 1];
            float4 sk0 = ((const float4*)(skip + (size_t)n * HC))[t * 2];
            float4 sk1 = ((const float4*)(skip + (size_t)n * HC))[t * 2 + 1];
            float bb[8] = {bv0.x, bv0.y, bv0.z, bv0.w, bv1.x, bv1.y, bv1.z, bv1.w};
            float sk[8] = {sk0.x, sk0.y, sk0.z, sk0.w, sk1.x, sk1.y, sk1.z, sk1.w};
            ushort8v ov;
            #pragma unroll
            for (int c = 0; c < 8; ++c) {
                float r = o[c] + bb[c] + sk[c];
                r = r > 0.f ? r : (__expf(r) - 1.f);   // ELU
                ov[c] = f2bf(r);
            }
            *(ushort8v*)((unsigned short*)out + (size_t)n * HC + t * 8) = ov;
        }
    } else {
        float r4[8], r8[8], r12[8];
        #pragma unroll
        for (int c = 0; c < 8; ++c) {
            r4[c]  = __shfl_down(o[c], 4, 64);
            r8[c]  = __shfl_down(o[c], 8, 64);
            r12[c] = __shfl_down(o[c], 12, 64);
        }
        if (lane < 4) {
            float* op = (float*)out + (size_t)n * NC + lane * 8;
            float rr[8];
            #pragma unroll
            for (int c = 0; c < 8; ++c) {
                rr[c] = 0.25f * (o[c] + r4[c] + r8[c] + r12[c])
                      + bias[lane * 8 + c] + skip[(size_t)n * NC + lane * 8 + c];
            }
            *(float4*)op = (float4){rr[0], rr[1], rr[2], rr[3]};
            *(float4*)(op + 4) = (float4){rr[4], rr[5], rr[6], rr[7]};
        }
    }
}

// ---------------- phase kernels ----------------

// transpose all 6 weight matrices to bf16 Wt[n][k] AND zero deg (extra blocks)
__global__ void k_prep(const float* __restrict__ W0, const float* __restrict__ S0,
                       const float* __restrict__ W1, const float* __restrict__ S1,
                       const float* __restrict__ W2, const float* __restrict__ S2,
                       unsigned short* __restrict__ wt, int* __restrict__ deg) {
    int idx = blockIdx.x * blockDim.x + threadIdx.x;
    if (idx < WT_TOTAL) {
        const float* W; int OD; int base;
        int r = idx >> 14;
        if (idx < 81920) {
            OD = 128; base = r << 14;
            W = (r == 0) ? W0 : (r == 1) ? S0 : (r == 2) ? W1 : (r == 3) ? S1 : W2;
        } else { W = S2; OD = 32; base = 81920; }
        int off = idx - base;
        int n = off >> 7, k = off & 127;
        wt[idx] = f2bf(W[(size_t)k * OD + n]);
    } else {
        int i = idx - WT_TOTAL;
        if (i < NN) deg[i] = 0;
    }
}

__global__ void k_hist(const int* __restrict__ dst, int* __restrict__ deg) {
    int e = blockIdx.x * blockDim.x + threadIdx.x;
    if (e < NE) atomicAdd(&deg[dst[e]], 1);
}

__global__ __launch_bounds__(NTHR) void k_scan1(const int* __restrict__ deg,
                                                int* __restrict__ partial,
                                                int* __restrict__ blocksum) {
    __shared__ int sh[NTHR];
    int b = blockIdx.x, t = threadIdx.x;
    int i = b * NTHR + t;
    int d = (i < NN) ? deg[i] : 0;
    sh[t] = d;
    __syncthreads();
    #pragma unroll
    for (int off = 1; off < NTHR; off <<= 1) {
        int v = (t >= off) ? sh[t - off] : 0;
        __syncthreads();
        sh[t] += v;
        __syncthreads();
    }
    if (i < NN) partial[i] = sh[t];
    if (t == NTHR - 1) blocksum[b] = sh[t];
}

// merged scan2+scan3: each block scans all 196 tile sums in-LDS (redundant,
// trivial), then applies its tile's exclusive offset -> rowptr, cursor.
__global__ __launch_bounds__(NTHR) void k_scan23(const int* __restrict__ deg,
                                                 const int* __restrict__ partial,
                                                 const int* __restrict__ blocksum,
                                                 int* __restrict__ rowptr,
                                                 int* __restrict__ cursor) {
    __shared__ int sh[NTHR];
    int b = blockIdx.x, t = threadIdx.x;
    int v = (t < NTILE) ? blocksum[t] : 0;
    sh[t] = v;
    __syncthreads();
    #pragma unroll
    for (int off = 1; off < NTHR; off <<= 1) {
        int u = (t >= off) ? sh[t - off] : 0;
        __syncthreads();
        sh[t] += u;
        __syncthreads();
    }
    // exclusive prefix for tile b
    int tile_off = (b > 0) ? sh[b - 1] : 0;
    int i = b * NTHR + t;
    if (i < NN) {
        int inc = partial[i] + tile_off;
        rowptr[i + 1] = inc;
        cursor[i] = inc - deg[i];
        if (i == 0) rowptr[0] = 0;
    }
}

__global__ void k_scatter(const int* __restrict__ src, const int* __restrict__ dst,
                          int* __restrict__ cursor, int* __restrict__ csr_src) {
    int e = blockIdx.x * blockDim.x + threadIdx.x;
    if (e >= NE) return;
    int d = dst[e];
    int pos = atomicAdd(&cursor[d], 1);
    csr_src[pos] = src[e];
}

template<typename AT>
__global__ __launch_bounds__(256) void k_gemm_dual_lf(
    const AT* __restrict__ x,
    const unsigned short* __restrict__ Wta, const float* __restrict__ ba, unsigned short* __restrict__ ya,
    const unsigned short* __restrict__ Wtb, const float* __restrict__ bb, float* __restrict__ yb) {
    int wid = threadIdx.x >> 6, lane = threadIdx.x & 63;
    int n0 = (blockIdx.x * 4 + wid) * 32;
    if (n0 >= NN) return;
    if (blockIdx.y == 0) gemm_wave<AT, 128, 1>(x, Wta, ba, (void*)ya, n0, lane);
    else                 gemm_wave<AT, 128, 0>(x, Wtb, bb, (void*)yb, n0, lane);
}

__global__ __launch_bounds__(256) void k_gemm_dual_l2(
    const unsigned short* __restrict__ x,
    const unsigned short* __restrict__ Wta, const float* __restrict__ ba, unsigned short* __restrict__ ya,
    const unsigned short* __restrict__ Wtb, const float* __restrict__ bb, float* __restrict__ yb) {
    int wid = threadIdx.x >> 6, lane = threadIdx.x & 63;
    int n0 = (blockIdx.x * 4 + wid) * 32;
    if (n0 >= NN) return;
    if (blockIdx.y == 0) gemm_wave<unsigned short, 128, 1>(x, Wta, ba, (void*)ya, n0, lane);
    else                 gemm_wave<unsigned short, 32, 0>(x, Wtb, bb, (void*)yb, n0, lane);
}

__global__ __launch_bounds__(256) void k_gat(
    const unsigned short* __restrict__ h, const int* __restrict__ rowptr,
    const int* __restrict__ csr_src, const float* __restrict__ att,
    const float* __restrict__ bias, const float* __restrict__ skip,
    void* __restrict__ out, int last) {
    int wid = threadIdx.x >> 6;
    int n = blockIdx.x * 4 + wid;
    if (n >= NN) return;
    gat_node(n, threadIdx.x & 63, h, rowptr, csr_src, att, bias, skip, out, last);
}

extern "C" void kernel_launch(void* const* d_in, const int* in_sizes, int n_in,
                              void* d_out, int out_size, void* d_ws, size_t ws_size,
                              hipStream_t stream) {
    const float* x0 = (const float*)d_in[0];
    const int* ei = (const int*)d_in[1];
    const int* src = ei;
    const int* dst = ei + NE;

    unsigned short* xbuf = (unsigned short*)d_ws;            // NN*HC bf16
    unsigned short* h    = xbuf + (size_t)NN * HC;           // NN*HC bf16
    float* skip  = (float*)(h + (size_t)NN * HC);            // NN*HC fp32
    int* deg     = (int*)(skip + (size_t)NN * HC);           // NN
    int* rowptr  = deg + NN;                                 // NN+1
    int* cursor  = rowptr + NN + 1;                          // NN
    int* partial = cursor + NN;                              // NN
    int* blocksum = partial + NN;                            // NTILE
    uintptr_t pa = (uintptr_t)(blocksum + NTILE);
    pa = (pa + 15) & ~(uintptr_t)15;
    unsigned short* wt = (unsigned short*)pa;                // WT_TOTAL bf16
    int* csr_src = (int*)(wt + WT_TOTAL);                    // NE

    unsigned short* wtW[3] = {wt, wt + 32768, wt + 65536};
    unsigned short* wtS[3] = {wt + 16384, wt + 49152, wt + 81920};

    // ---- CSR build + weight prep (5 dispatches) ----
    k_prep<<<(WT_TOTAL + NN + 255) / 256, 256, 0, stream>>>(
        (const float*)d_in[2], (const float*)d_in[6],
        (const float*)d_in[8], (const float*)d_in[12],
        (const float*)d_in[14], (const float*)d_in[18], wt, deg);
    k_hist<<<(NE + 255) / 256, 256, 0, stream>>>(dst, deg);
    k_scan1<<<NTILE, NTHR, 0, stream>>>(deg, partial, blocksum);
    k_scan23<<<NTILE, NTHR, 0, stream>>>(deg, partial, blocksum, rowptr, cursor);
    k_scatter<<<(NE + 255) / 256, 256, 0, stream>>>(src, dst, cursor, csr_src);

    const int GLF = (NN + 127) / 128;
    const int GGAT = (NN + 3) / 4;

    for (int l = 0; l < 3; ++l) {
        const float* linb  = (const float*)d_in[2 + 6 * l + 1];
        const float* att   = (const float*)d_in[2 + 6 * l + 2];
        const float* bias  = (const float*)d_in[2 + 6 * l + 3];
        const float* skipb = (const float*)d_in[2 + 6 * l + 5];

        if (l == 0) {
            k_gemm_dual_lf<float><<<dim3(GLF, 2), 256, 0, stream>>>(
                x0, wtW[0], linb, h, wtS[0], skipb, skip);
        } else if (l == 1) {
            k_gemm_dual_lf<unsigned short><<<dim3(GLF, 2), 256, 0, stream>>>(
                xbuf, wtW[1], linb, h, wtS[1], skipb, skip);
        } else {
            k_gemm_dual_l2<<<dim3(GLF, 2), 256, 0, stream>>>(
                xbuf, wtW[2], linb, h, wtS[2], skipb, skip);
        }
        void* outp = (l < 2) ? (void*)xbuf : (void*)d_out;
        k_gat<<<GGAT, 256, 0, stream>>>(h, rowptr, csr_src, att, bias, skip, outp, l == 2);
    }
}

// Round 16
// 357.078 us; speedup vs baseline: 4.9375x; 1.0199x over previous
//
#include <hip/hip_runtime.h>
#include <hip/hip_bf16.h>

#define NN 50000
#define NE 600000
#define IN_DIM 128
#define HC 128      // H*C
#define NH 4
#define NC 32
#define NEG_SLOPE 0.2f

#define NTHR 256
#define NTILE 196           // ceil(NN/256) scan tiles
#define WT_TOTAL 86016

typedef __attribute__((ext_vector_type(8))) short short8;
typedef __attribute__((ext_vector_type(4))) float floatx4;
typedef __attribute__((ext_vector_type(8))) unsigned short ushort8v;

__device__ __forceinline__ float bf2f(unsigned short u) {
    return __uint_as_float(((unsigned)u) << 16);
}
__device__ __forceinline__ unsigned short f2bf(float f) {
    unsigned u = __float_as_uint(f);
    unsigned r = (u + 0x7FFFu + ((u >> 16) & 1u)) >> 16;   // RNE
    return (unsigned short)r;
}

// ============ LDS-free MFMA GEMM wave: 32 rows x OD cols, K=128 ============
// mfma(A=Wt frag, B=x frag) -> D[m=channel][n=node]; packed bf16 stores.
template<typename AT, int OD>
__device__ __forceinline__ void gemm_wave(
    const AT* __restrict__ x, const unsigned short* __restrict__ Wt,
    const float* __restrict__ b, unsigned short* __restrict__ y, int n0, int lane) {
    int quad = lane >> 4, l16 = lane & 15;
    floatx4 acc[2][OD / 16];
    #pragma unroll
    for (int i = 0; i < 2; ++i)
        #pragma unroll
        for (int j = 0; j < OD / 16; ++j) acc[i][j] = (floatx4){0.f, 0.f, 0.f, 0.f};

    int r0 = n0 + l16;      if (r0 >= NN) r0 = NN - 1;
    int r1 = n0 + 16 + l16; if (r1 >= NN) r1 = NN - 1;

    #pragma unroll
    for (int ks = 0; ks < 4; ++ks) {
        int kb = ks * 32 + quad * 8;
        short8 xb0, xb1;
        if constexpr (sizeof(AT) == 4) {
            const float* xr = (const float*)x;
            float4 v0 = *(const float4*)&xr[(size_t)r0 * IN_DIM + kb];
            float4 v1 = *(const float4*)&xr[(size_t)r0 * IN_DIM + kb + 4];
            float4 u0 = *(const float4*)&xr[(size_t)r1 * IN_DIM + kb];
            float4 u1 = *(const float4*)&xr[(size_t)r1 * IN_DIM + kb + 4];
            xb0 = (short8){(short)f2bf(v0.x), (short)f2bf(v0.y), (short)f2bf(v0.z), (short)f2bf(v0.w),
                           (short)f2bf(v1.x), (short)f2bf(v1.y), (short)f2bf(v1.z), (short)f2bf(v1.w)};
            xb1 = (short8){(short)f2bf(u0.x), (short)f2bf(u0.y), (short)f2bf(u0.z), (short)f2bf(u0.w),
                           (short)f2bf(u1.x), (short)f2bf(u1.y), (short)f2bf(u1.z), (short)f2bf(u1.w)};
        } else {
            xb0 = *(const short8*)&((const unsigned short*)x)[(size_t)r0 * IN_DIM + kb];
            xb1 = *(const short8*)&((const unsigned short*)x)[(size_t)r1 * IN_DIM + kb];
        }
        #pragma unroll
        for (int tc = 0; tc < OD / 16; ++tc) {
            short8 af = *(const short8*)&Wt[(size_t)(tc * 16 + l16) * 128 + kb];
            acc[0][tc] = __builtin_amdgcn_mfma_f32_16x16x32_bf16(af, xb0, acc[0][tc], 0, 0, 0);
            acc[1][tc] = __builtin_amdgcn_mfma_f32_16x16x32_bf16(af, xb1, acc[1][tc], 0, 0, 0);
        }
    }

    #pragma unroll
    for (int tc = 0; tc < OD / 16; ++tc) {
        int cbase = tc * 16 + quad * 4;
        float4 bv = *(const float4*)&b[cbase];
        #pragma unroll
        for (int i = 0; i < 2; ++i) {
            int node = n0 + i * 16 + l16;
            if (node < NN) {
                ushort4 pk = {f2bf(acc[i][tc][0] + bv.x), f2bf(acc[i][tc][1] + bv.y),
                              f2bf(acc[i][tc][2] + bv.z), f2bf(acc[i][tc][3] + bv.w)};
                *(ushort4*)&y[(size_t)node * OD + cbase] = pk;
            }
        }
    }
}

// ---------------- per-node GATv2 (1 wave, 4 slots x 16 lanes) ----------------
// Score via leaky(v) = 0.6v + 0.4|v|:
//   part = 0.6*(K + sum hs*att) + 0.4*sum |hs+hd|*att,  K = sum hd*att (per node).
__device__ __forceinline__ void gat_node(
    int n, int lane, const unsigned short* __restrict__ h, const int* __restrict__ rowptr,
    const int* __restrict__ csr_src, const float* __restrict__ att,
    const float* __restrict__ bias, const unsigned short* __restrict__ skip,
    void* __restrict__ out, int last) {
    int slot = lane >> 4;
    int t = lane & 15;

    ushort8v hdv = *(const ushort8v*)(h + (size_t)n * HC + t * 8);
    float hd[8], av[8];
    #pragma unroll
    for (int c = 0; c < 8; ++c) hd[c] = bf2f(hdv[c]);
    float4 av0 = ((const float4*)att)[t * 2];
    float4 av1 = ((const float4*)att)[t * 2 + 1];
    av[0] = av0.x; av[1] = av0.y; av[2] = av0.z; av[3] = av0.w;
    av[4] = av1.x; av[5] = av1.y; av[6] = av1.z; av[7] = av1.w;

    float K = 0.f;
    #pragma unroll
    for (int c = 0; c < 8; ++c) K = fmaf(hd[c], av[c], K);

    int beg = rowptr[n], end = rowptr[n + 1];
    float l = 0.f;
    float acc[8] = {};

    int i0 = beg + slot;
    ushort8v b0 = 0, b1 = 0;
    if (i0 < end)     b0 = *(const ushort8v*)(h + (size_t)csr_src[i0] * HC + t * 8);
    if (i0 + 4 < end) b1 = *(const ushort8v*)(h + (size_t)csr_src[i0 + 4] * HC + t * 8);

    for (int i = i0; i < end; i += 4) {
        float hs[8];
        float S1 = K, S2 = 0.f;
        #pragma unroll
        for (int c = 0; c < 8; ++c) {
            float hsv = bf2f(b0[c]);
            hs[c] = hsv;
            S1 = fmaf(hsv, av[c], S1);
            S2 = fmaf(fabsf(hsv + hd[c]), av[c], S2);   // abs folds into FMA modifier
        }
        b0 = b1;
        if (i + 8 < end)
            b1 = *(const ushort8v*)(h + (size_t)csr_src[i + 8] * HC + t * 8);
        float part = fmaf(0.6f, S1, 0.4f * S2);
        part += __shfl_xor(part, 1, 64);   // reduce over 4-lane head group
        part += __shfl_xor(part, 2, 64);
        float p = __expf(part);
        #pragma unroll
        for (int c = 0; c < 8; ++c) acc[c] = fmaf(p, hs[c], acc[c]);
        l += p;
    }

    // merge the 4 slots (lane quadrants) via cross-lane xor sums
    l += __shfl_xor(l, 16, 64);
    l += __shfl_xor(l, 32, 64);
    #pragma unroll
    for (int c = 0; c < 8; ++c) {
        acc[c] += __shfl_xor(acc[c], 16, 64);
        acc[c] += __shfl_xor(acc[c], 32, 64);
    }

    float inv = 1.f / fmaxf(l, 1e-16f);
    float o[8];
    #pragma unroll
    for (int c = 0; c < 8; ++c) o[c] = acc[c] * inv;

    if (!last) {
        if (lane < 16) {
            float4 bv0 = ((const float4*)bias)[t * 2];
            float4 bv1 = ((const float4*)bias)[t * 2 + 1];
            float bb[8] = {bv0.x, bv0.y, bv0.z, bv0.w, bv1.x, bv1.y, bv1.z, bv1.w};
            ushort8v skv = *(const ushort8v*)(skip + (size_t)n * HC + t * 8);
            ushort8v ov;
            #pragma unroll
            for (int c = 0; c < 8; ++c) {
                float r = o[c] + bb[c] + bf2f(skv[c]);
                r = r > 0.f ? r : (__expf(r) - 1.f);   // ELU
                ov[c] = f2bf(r);
            }
            *(ushort8v*)((unsigned short*)out + (size_t)n * HC + t * 8) = ov;
        }
    } else {
        float r4[8], r8[8], r12[8];
        #pragma unroll
        for (int c = 0; c < 8; ++c) {
            r4[c]  = __shfl_down(o[c], 4, 64);
            r8[c]  = __shfl_down(o[c], 8, 64);
            r12[c] = __shfl_down(o[c], 12, 64);
        }
        if (lane < 4) {
            float* op = (float*)out + (size_t)n * NC + lane * 8;
            ushort8v skv = *(const ushort8v*)(skip + (size_t)n * NC + lane * 8);
            float rr[8];
            #pragma unroll
            for (int c = 0; c < 8; ++c) {
                rr[c] = 0.25f * (o[c] + r4[c] + r8[c] + r12[c])
                      + bias[lane * 8 + c] + bf2f(skv[c]);
            }
            *(float4*)op = (float4){rr[0], rr[1], rr[2], rr[3]};
            *(float4*)(op + 4) = (float4){rr[4], rr[5], rr[6], rr[7]};
        }
    }
}

// ---------------- phase kernels ----------------

// transpose all 6 weight matrices to bf16 Wt[n][k] AND zero deg (extra blocks)
__global__ void k_prep(const float* __restrict__ W0, const float* __restrict__ S0,
                       const float* __restrict__ W1, const float* __restrict__ S1,
                       const float* __restrict__ W2, const float* __restrict__ S2,
                       unsigned short* __restrict__ wt, int* __restrict__ deg) {
    int idx = blockIdx.x * blockDim.x + threadIdx.x;
    if (idx < WT_TOTAL) {
        const float* W; int OD; int base;
        int r = idx >> 14;
        if (idx < 81920) {
            OD = 128; base = r << 14;
            W = (r == 0) ? W0 : (r == 1) ? S0 : (r == 2) ? W1 : (r == 3) ? S1 : W2;
        } else { W = S2; OD = 32; base = 81920; }
        int off = idx - base;
        int n = off >> 7, k = off & 127;
        wt[idx] = f2bf(W[(size_t)k * OD + n]);
    } else {
        int i = idx - WT_TOTAL;
        if (i < NN) deg[i] = 0;
    }
}

__global__ void k_hist(const int* __restrict__ dst, int* __restrict__ deg) {
    int e = blockIdx.x * blockDim.x + threadIdx.x;
    if (e < NE) atomicAdd(&deg[dst[e]], 1);
}

__global__ __launch_bounds__(NTHR) void k_scan1(const int* __restrict__ deg,
                                                int* __restrict__ partial,
                                                int* __restrict__ blocksum) {
    __shared__ int sh[NTHR];
    int b = blockIdx.x, t = threadIdx.x;
    int i = b * NTHR + t;
    int d = (i < NN) ? deg[i] : 0;
    sh[t] = d;
    __syncthreads();
    #pragma unroll
    for (int off = 1; off < NTHR; off <<= 1) {
        int v = (t >= off) ? sh[t - off] : 0;
        __syncthreads();
        sh[t] += v;
        __syncthreads();
    }
    if (i < NN) partial[i] = sh[t];
    if (t == NTHR - 1) blocksum[b] = sh[t];
}

// merged scan2+scan3: each block scans all 196 tile sums in-LDS (redundant,
// trivial), then applies its tile's exclusive offset -> rowptr, cursor.
__global__ __launch_bounds__(NTHR) void k_scan23(const int* __restrict__ deg,
                                                 const int* __restrict__ partial,
                                                 const int* __restrict__ blocksum,
                                                 int* __restrict__ rowptr,
                                                 int* __restrict__ cursor) {
    __shared__ int sh[NTHR];
    int b = blockIdx.x, t = threadIdx.x;
    int v = (t < NTILE) ? blocksum[t] : 0;
    sh[t] = v;
    __syncthreads();
    #pragma unroll
    for (int off = 1; off < NTHR; off <<= 1) {
        int u = (t >= off) ? sh[t - off] : 0;
        __syncthreads();
        sh[t] += u;
        __syncthreads();
    }
    int tile_off = (b > 0) ? sh[b - 1] : 0;
    int i = b * NTHR + t;
    if (i < NN) {
        int inc = partial[i] + tile_off;
        rowptr[i + 1] = inc;
        cursor[i] = inc - deg[i];
        if (i == 0) rowptr[0] = 0;
    }
}

__global__ void k_scatter(const int* __restrict__ src, const int* __restrict__ dst,
                          int* __restrict__ cursor, int* __restrict__ csr_src) {
    int e = blockIdx.x * blockDim.x + threadIdx.x;
    if (e >= NE) return;
    int d = dst[e];
    int pos = atomicAdd(&cursor[d], 1);
    csr_src[pos] = src[e];
}

template<typename AT>
__global__ __launch_bounds__(256) void k_gemm_dual_lf(
    const AT* __restrict__ x,
    const unsigned short* __restrict__ Wta, const float* __restrict__ ba, unsigned short* __restrict__ ya,
    const unsigned short* __restrict__ Wtb, const float* __restrict__ bb, unsigned short* __restrict__ yb) {
    int wid = threadIdx.x >> 6, lane = threadIdx.x & 63;
    int n0 = (blockIdx.x * 4 + wid) * 32;
    if (n0 >= NN) return;
    if (blockIdx.y == 0) gemm_wave<AT, 128>(x, Wta, ba, ya, n0, lane);
    else                 gemm_wave<AT, 128>(x, Wtb, bb, yb, n0, lane);
}

__global__ __launch_bounds__(256) void k_gemm_dual_l2(
    const unsigned short* __restrict__ x,
    const unsigned short* __restrict__ Wta, const float* __restrict__ ba, unsigned short* __restrict__ ya,
    const unsigned short* __restrict__ Wtb, const float* __restrict__ bb, unsigned short* __restrict__ yb) {
    int wid = threadIdx.x >> 6, lane = threadIdx.x & 63;
    int n0 = (blockIdx.x * 4 + wid) * 32;
    if (n0 >= NN) return;
    if (blockIdx.y == 0) gemm_wave<unsigned short, 128>(x, Wta, ba, ya, n0, lane);
    else                 gemm_wave<unsigned short, 32>(x, Wtb, bb, yb, n0, lane);
}

__global__ __launch_bounds__(256) void k_gat(
    const unsigned short* __restrict__ h, const int* __restrict__ rowptr,
    const int* __restrict__ csr_src, const float* __restrict__ att,
    const float* __restrict__ bias, const unsigned short* __restrict__ skip,
    void* __restrict__ out, int last) {
    int wid = threadIdx.x >> 6;
    int n = blockIdx.x * 4 + wid;
    if (n >= NN) return;
    gat_node(n, threadIdx.x & 63, h, rowptr, csr_src, att, bias, skip, out, last);
}

extern "C" void kernel_launch(void* const* d_in, const int* in_sizes, int n_in,
                              void* d_out, int out_size, void* d_ws, size_t ws_size,
                              hipStream_t stream) {
    const float* x0 = (const float*)d_in[0];
    const int* ei = (const int*)d_in[1];
    const int* src = ei;
    const int* dst = ei + NE;

    unsigned short* xbuf = (unsigned short*)d_ws;            // NN*HC bf16
    unsigned short* h    = xbuf + (size_t)NN * HC;           // NN*HC bf16
    unsigned short* skip = h + (size_t)NN * HC;              // NN*HC bf16
    int* deg     = (int*)(skip + (size_t)NN * HC);           // NN
    int* rowptr  = deg + NN;                                 // NN+1
    int* cursor  = rowptr + NN + 1;                          // NN
    int* partial = cursor + NN;                              // NN
    int* blocksum = partial + NN;                            // NTILE
    uintptr_t pa = (uintptr_t)(blocksum + NTILE);
    pa = (pa + 15) & ~(uintptr_t)15;
    unsigned short* wt = (unsigned short*)pa;                // WT_TOTAL bf16
    int* csr_src = (int*)(wt + WT_TOTAL);                    // NE

    unsigned short* wtW[3] = {wt, wt + 32768, wt + 65536};
    unsigned short* wtS[3] = {wt + 16384, wt + 49152, wt + 81920};

    // ---- CSR build + weight prep (5 dispatches) ----
    k_prep<<<(WT_TOTAL + NN + 255) / 256, 256, 0, stream>>>(
        (const float*)d_in[2], (const float*)d_in[6],
        (const float*)d_in[8], (const float*)d_in[12],
        (const float*)d_in[14], (const float*)d_in[18], wt, deg);
    k_hist<<<(NE + 255) / 256, 256, 0, stream>>>(dst, deg);
    k_scan1<<<NTILE, NTHR, 0, stream>>>(deg, partial, blocksum);
    k_scan23<<<NTILE, NTHR, 0, stream>>>(deg, partial, blocksum, rowptr, cursor);
    k_scatter<<<(NE + 255) / 256, 256, 0, stream>>>(src, dst, cursor, csr_src);

    const int GLF = (NN + 127) / 128;
    const int GGAT = (NN + 3) / 4;

    for (int l = 0; l < 3; ++l) {
        const float* linb  = (const float*)d_in[2 + 6 * l + 1];
        const float* att   = (const float*)d_in[2 + 6 * l + 2];
        const float* bias  = (const float*)d_in[2 + 6 * l + 3];
        const float* skipb = (const float*)d_in[2 + 6 * l + 5];

        if (l == 0) {
            k_gemm_dual_lf<float><<<dim3(GLF, 2), 256, 0, stream>>>(
                x0, wtW[0], linb, h, wtS[0], skipb, skip);
        } else if (l == 1) {
            k_gemm_dual_lf<unsigned short><<<dim3(GLF, 2), 256, 0, stream>>>(
                xbuf, wtW[1], linb, h, wtS[1], skipb, skip);
        } else {
            k_gemm_dual_l2<<<dim3(GLF, 2), 256, 0, stream>>>(
                xbuf, wtW[2], linb, h, wtS[2], skipb, skip);
        }
        void* outp = (l < 2) ? (void*)xbuf : (void*)d_out;
        k_gat<<<GGAT, 256, 0, stream>>>(h, rowptr, csr_src, att, bias, skip, outp, l == 2);
    }
}